// Round 8
// baseline (179.355 us; speedup 1.0000x reference)
//
#include <hip/hip_runtime.h>
#include <stdint.h>

// FP32 in/out. bf16 only for MFMA operands.
// R21: R20's 4-head split failed co-residency: LDS 81,408B rounds to 80KB,
// 2x80 = exactly 160KB -> HW needs slack, stayed 1 block/CU (Occ 19.9%,
// 47.6us). Fix: alias hv onto K region of qlds (K dead after S-dots bar4;
// zero hv during softmax phase) -> LDS = 74,880B, 2x~75KB = 150KB < 160KB
// -> true 2 blocks/CU = 4 waves/SIMD. Geometry/numerics byte-identical.
// Ledger: R20 occupancy blocked by LDS rounding; R19 k_final 512thr (167.0
// best); R18 1024-thr VGPR-64 spill (WRITE 31MB scratch); R17 atomic stats;
// R16 fuse qkv+attn; R10 launch_bounds min-waves spill -- NO 2nd arg.

#define N_NODES 6144
#define GSIZE 24
#define NGRAPH 256
#define DIN 128
#define DH 64
#define EFF 512
#define EPSN 1e-5f

typedef __attribute__((ext_vector_type(8))) __bf16 bf16x8;
typedef __attribute__((ext_vector_type(4))) float f32x4;
union U16B { uint4 u; bf16x8 v; unsigned short s[8]; };

__device__ inline unsigned short f2bf(float f){
  unsigned u = __float_as_uint(f);
  u += 0x7fff + ((u>>16)&1);
  return (unsigned short)(u>>16);
}
__device__ inline float gelu_exact(float x){ return 0.5f*x*(1.0f+erff(x*0.70710678118654752f)); }

// ---- workspace float offsets ----
#define XS    0          // 256 floats: x col sum+sumsq, ATOMIC
#define HS    256        // 128 floats: h col sum+sumsq, ATOMIC
#define HCF   384        // hcomb: 6144 x 64 fp32 (atomic-accumulated), ends 393600
#define WT1   393600
#define WT2   397696
#define PWT1  401792
#define FBo   405888     // 257 floats
#define WCVT_BYTE  1703936   // 3 x 512 x 128 bf16 = 393216 B

#define QS3 260          // fp32 row stride, 4-head QKV tile (1040 B, 16B-aligned)

// ================= K1: k_pre =================
__global__ __launch_bounds__(256)
void k_pre(const float* __restrict__ x,
           const float* __restrict__ o_w1, const float* __restrict__ o_w2,
           const float* __restrict__ p_w1,
           const float* __restrict__ o_b1, const float* __restrict__ o_b2,
           const float* __restrict__ p_b1, const float* __restrict__ p_w2,
           const float* __restrict__ p_b2,
           const float* __restrict__ wq, const float* __restrict__ wk,
           const float* __restrict__ wv,
           float* __restrict__ wsf){
  int t = threadIdx.x;
  int bi = blockIdx.x;
  if(bi < 192){
    int c = t & 127, h = t >> 7;
    float s = 0.f, q = 0.f;
    #pragma unroll
    for(int r = 0; r < 16; ++r){
      float v = x[(size_t)(bi*32 + h + 2*r)*DIN + c];
      s += v; q += v*v;
    }
    __shared__ float sm[256], sm2[256];
    sm[t] = s; sm2[t] = q;
    __syncthreads();
    if(t < 128){
      atomicAdd(&wsf[XS + t],       sm[t] + sm[t+128]);
      atomicAdd(&wsf[XS + 128 + t], sm2[t] + sm2[t+128]);
    }
    return;
  }
  if(bi < 195){
    const float* src; float* dst;
    if(bi == 192){ src = o_w1; dst = wsf + WT1; }
    else if(bi == 193){ src = o_w2; dst = wsf + WT2; }
    else { src = p_w1; dst = wsf + PWT1; }
    for(int p = t; p < DH*DH; p += 256){
      int r = p >> 6, c = p & 63;
      dst[c*DH + r] = src[p];
    }
    if(bi == 192){
      float* fb = wsf + FBo;
      if(t < 64){
        fb[t]       = o_b1[t];
        fb[64 + t]  = o_b2[t];
        fb[128 + t] = p_b1[t];
        fb[192 + t] = p_w2[t];
      }
      if(t == 0) fb[256] = p_b2[0];
    }
    return;
  }
  int j = bi - 195;               // 0..11
  int mat = j >> 2, seg = j & 3;
  const float* src = (mat==0) ? wq : (mat==1) ? wk : wv;
  unsigned short* dst = (unsigned short*)((char*)wsf + WCVT_BYTE)
                        + (size_t)mat*EFF*DIN + seg*16384;
  const float* sp = src + seg*16384;
  for(int e = t*8; e < 16384; e += 2048){
    float4 a = *(const float4*)(sp + e);
    float4 b = *(const float4*)(sp + e + 4);
    U16B o;
    o.s[0]=f2bf(a.x); o.s[1]=f2bf(a.y); o.s[2]=f2bf(a.z); o.s[3]=f2bf(a.w);
    o.s[4]=f2bf(b.x); o.s[5]=f2bf(b.y); o.s[6]=f2bf(b.z); o.s[7]=f2bf(b.w);
    *(uint4*)(dst + e) = o.u;
  }
}

// ---- QKV weight tile macros (4-head block: gh = global head, hh = local) ----
#define LOADW3(nt, W, B) do{ \
  const int mat_ = (nt)>>2, sub_ = (nt)&3; \
  const unsigned short* wp_ = wcvt + (size_t)mat_*EFF*DIN \
      + (size_t)(gh*64 + sub_*16 + m)*DIN + lq*8; \
  W[0] = *(const uint4*)(wp_);      W[1] = *(const uint4*)(wp_ + 32); \
  W[2] = *(const uint4*)(wp_ + 64); W[3] = *(const uint4*)(wp_ + 96); \
  const float* bias_ = (mat_==0) ? bq : (mat_==1) ? bk : bv; \
  B = *(const float4*)(bias_ + gh*64 + sub_*16 + lq*4); \
}while(0)

#define COMPW3(nt, W, B) do{ \
  const int mat_ = (nt)>>2, sub_ = (nt)&3; \
  f32x4 a0_ = {0.f,0.f,0.f,0.f}, a1_ = {0.f,0.f,0.f,0.f}; \
  U16B w8_; \
  w8_.u = W[0]; \
  a0_ = __builtin_amdgcn_mfma_f32_16x16x32_bf16(w8_.v, afr[0][0], a0_, 0, 0, 0); \
  a1_ = __builtin_amdgcn_mfma_f32_16x16x32_bf16(w8_.v, afr[1][0], a1_, 0, 0, 0); \
  w8_.u = W[1]; \
  a0_ = __builtin_amdgcn_mfma_f32_16x16x32_bf16(w8_.v, afr[0][1], a0_, 0, 0, 0); \
  a1_ = __builtin_amdgcn_mfma_f32_16x16x32_bf16(w8_.v, afr[1][1], a1_, 0, 0, 0); \
  w8_.u = W[2]; \
  a0_ = __builtin_amdgcn_mfma_f32_16x16x32_bf16(w8_.v, afr[0][2], a0_, 0, 0, 0); \
  a1_ = __builtin_amdgcn_mfma_f32_16x16x32_bf16(w8_.v, afr[1][2], a1_, 0, 0, 0); \
  w8_.u = W[3]; \
  a0_ = __builtin_amdgcn_mfma_f32_16x16x32_bf16(w8_.v, afr[0][3], a0_, 0, 0, 0); \
  a1_ = __builtin_amdgcn_mfma_f32_16x16x32_bf16(w8_.v, afr[1][3], a1_, 0, 0, 0); \
  float* dst_ = qlds + mat_*(GSIZE*QS3); \
  const int col_ = hh*64 + sub_*16 + lq*4; \
  { float4 o_; o_.x=a0_[0]+B.x; o_.y=a0_[1]+B.y; o_.z=a0_[2]+B.z; o_.w=a0_[3]+B.w; \
    *(float4*)(dst_ + m*QS3 + col_) = o_; } \
  if(m < 8){ float4 o_; o_.x=a1_[0]+B.x; o_.y=a1_[1]+B.y; o_.z=a1_[2]+B.z; o_.w=a1_[3]+B.w; \
    *(float4*)(dst_ + (16+m)*QS3 + col_) = o_; } \
}while(0)

// ================= K2: k_attn3 =================
// 512 blocks: block b = graph b>>1, heads (b&1)*4..+3. 512 thr = 8 waves =
// 2 waves/head (half = w&1). LDS = qlds ONLY (74,880B): A1/C1 alias Q region
// (dead before GEMM, fenced), hv aliases K region (dead after bar4, zeroed
// during softmax phase). -> 2 blocks/CU, 4 waves/SIMD.
__global__ __launch_bounds__(512)
void k_attn3(const float* __restrict__ x,
             const float* __restrict__ bq, const float* __restrict__ bk,
             const float* __restrict__ bv,
             const float* __restrict__ nq_w, const float* __restrict__ nq_b,
             const float* __restrict__ nq_ms,
             float* __restrict__ ws, float* __restrict__ hcomb){
  __shared__ __align__(16) float qlds[3*GSIZE*QS3];   // 74,880 B total
  float* A1s = qlds;                 // alias Q region (fenced by bar2)
  float* C1s = qlds + 128;
  float* hv  = qlds + GSIZE*QS3;     // alias K region ([24][64], zeroed post-bar4)

  int t = threadIdx.x, b = blockIdx.x;
  int base = (b >> 1)*GSIZE;
  int w = t >> 6, l = t & 63;
  int hh = w >> 1, half = w & 1;
  int gh = (b & 1)*4 + hh;
  const unsigned short* wcvt = (const unsigned short*)((const char*)ws + WCVT_BYTE);

  // ---- x-norm coeffs from atomic sums (into aliased A1s/C1s)
  if(t < 128){
    float s1 = ws[XS + t];
    float q1 = ws[XS + 128 + t];
    float mean = s1 * (1.0f / N_NODES);
    float ex2  = q1 * (1.0f / N_NODES);
    float cm   = mean * nq_ms[t];
    float var  = ex2 - 2.f*cm*mean + cm*cm;
    float rstd = rsqrtf(var + EPSN);
    float a    = nq_w[t] * rstd;
    A1s[t] = a; C1s[t] = nq_b[t] - a*cm;
  }
  __syncthreads();                                    // bar1: A1C1 ready

  int m = l & 15, lq = l >> 4;

  // ---- A-fragments (xhat bf16), rows mt*16+m (clamped)
  bf16x8 afr[2][4];
  #pragma unroll
  for(int mt = 0; mt < 2; ++mt){
    int row = mt*16 + m; if(row > GSIZE-1) row = GSIZE-1;
    const float* xr = x + (size_t)(base + row)*DIN;
    #pragma unroll
    for(int kk = 0; kk < 4; ++kk){
      int k0 = kk*32 + lq*8;
      float4 a = *(const float4*)(xr + k0);
      float4 b = *(const float4*)(xr + k0 + 4);
      U16B u;
      u.s[0] = f2bf(a.x*A1s[k0+0] + C1s[k0+0]);
      u.s[1] = f2bf(a.y*A1s[k0+1] + C1s[k0+1]);
      u.s[2] = f2bf(a.z*A1s[k0+2] + C1s[k0+2]);
      u.s[3] = f2bf(a.w*A1s[k0+3] + C1s[k0+3]);
      u.s[4] = f2bf(b.x*A1s[k0+4] + C1s[k0+4]);
      u.s[5] = f2bf(b.y*A1s[k0+5] + C1s[k0+5]);
      u.s[6] = f2bf(b.z*A1s[k0+6] + C1s[k0+6]);
      u.s[7] = f2bf(b.w*A1s[k0+7] + C1s[k0+7]);
      afr[mt][kk] = u.v;
    }
  }
  __syncthreads();                                    // bar2: A1C1 reads done (alias fence)

  // ---- QKV GEMM: wave (hh,half) does nt tiles half*6..+5, depth-2 prefetch
  {
    uint4 wA[4], wB[4], wC[4];
    float4 bA, bB, bC;
    int nb = half*6;
    LOADW3(nb+0, wA, bA);  LOADW3(nb+1, wB, bB);
    LOADW3(nb+2, wC, bC);  COMPW3(nb+0, wA, bA);
    LOADW3(nb+3, wA, bA);  COMPW3(nb+1, wB, bB);
    LOADW3(nb+4, wB, bB);  COMPW3(nb+2, wC, bC);
    LOADW3(nb+5, wC, bC);  COMPW3(nb+3, wA, bA);
    COMPW3(nb+4, wB, bB);
    COMPW3(nb+5, wC, bC);
  }
  __syncthreads();                                    // bar3: QKV complete

  // ---- S dots: rows half*12 + 3*(l>>4), cols 3*(l&7), K half d8=(l>>3)&1
  int r0 = half*12 + 3*(l >> 4), j0 = 3*(l & 7);
  float s00=0.f,s01=0.f,s02=0.f,s10=0.f,s11=0.f,s12=0.f,s20=0.f,s21=0.f,s22=0.f;
  {
    int d8 = (l >> 3) & 1;
    const float* qp = qlds + r0*QS3 + hh*64 + d8*32;
    const float* kp = qlds + GSIZE*QS3 + j0*QS3 + hh*64 + d8*32;
    #pragma unroll
    for(int d4 = 0; d4 < 8; ++d4){
      float4 q0 = *(const float4*)(qp + d4*4);
      float4 q1 = *(const float4*)(qp + QS3 + d4*4);
      float4 q2 = *(const float4*)(qp + 2*QS3 + d4*4);
      float4 k0 = *(const float4*)(kp + d4*4);
      float4 k1 = *(const float4*)(kp + QS3 + d4*4);
      float4 k2 = *(const float4*)(kp + 2*QS3 + d4*4);
      s00 += q0.x*k0.x + q0.y*k0.y + q0.z*k0.z + q0.w*k0.w;
      s01 += q0.x*k1.x + q0.y*k1.y + q0.z*k1.z + q0.w*k1.w;
      s02 += q0.x*k2.x + q0.y*k2.y + q0.z*k2.z + q0.w*k2.w;
      s10 += q1.x*k0.x + q1.y*k0.y + q1.z*k0.z + q1.w*k0.w;
      s11 += q1.x*k1.x + q1.y*k1.y + q1.z*k1.z + q1.w*k1.w;
      s12 += q1.x*k2.x + q1.y*k2.y + q1.z*k2.z + q1.w*k2.w;
      s20 += q2.x*k0.x + q2.y*k0.y + q2.z*k0.z + q2.w*k0.w;
      s21 += q2.x*k1.x + q2.y*k1.y + q2.z*k1.z + q2.w*k1.w;
      s22 += q2.x*k2.x + q2.y*k2.y + q2.z*k2.z + q2.w*k2.w;
    }
    s00 += __shfl_xor(s00, 8); s01 += __shfl_xor(s01, 8); s02 += __shfl_xor(s02, 8);
    s10 += __shfl_xor(s10, 8); s11 += __shfl_xor(s11, 8); s12 += __shfl_xor(s12, 8);
    s20 += __shfl_xor(s20, 8); s21 += __shfl_xor(s21, 8); s22 += __shfl_xor(s22, 8);
  }
  __syncthreads();                                    // bar4: all Q/K reads done

  // ---- softmax rows r0..r0+2 (ST overlays Q region) + zero hv (K region)
  {
    float a0, a1, a2, m0, su, inv;
    float* STb = qlds + hh*64;   // ST[j][r] at qlds[j*QS3 + hh*64 + r]
    a0 = s00*0.125f; a1 = s01*0.125f; a2 = s02*0.125f;
    m0 = fmaxf(fmaxf(a0, a1), a2);
    #pragma unroll
    for(int o = 1; o < 8; o <<= 1) m0 = fmaxf(m0, __shfl_xor(m0, o, 8));
    a0 = __expf(a0-m0); a1 = __expf(a1-m0); a2 = __expf(a2-m0);
    su = a0 + a1 + a2;
    #pragma unroll
    for(int o = 1; o < 8; o <<= 1) su += __shfl_xor(su, o, 8);
    inv = 1.0f/(su + 1e-16f);
    STb[(j0+0)*QS3 + r0] = a0*inv; STb[(j0+1)*QS3 + r0] = a1*inv; STb[(j0+2)*QS3 + r0] = a2*inv;
    a0 = s10*0.125f; a1 = s11*0.125f; a2 = s12*0.125f;
    m0 = fmaxf(fmaxf(a0, a1), a2);
    #pragma unroll
    for(int o = 1; o < 8; o <<= 1) m0 = fmaxf(m0, __shfl_xor(m0, o, 8));
    a0 = __expf(a0-m0); a1 = __expf(a1-m0); a2 = __expf(a2-m0);
    su = a0 + a1 + a2;
    #pragma unroll
    for(int o = 1; o < 8; o <<= 1) su += __shfl_xor(su, o, 8);
    inv = 1.0f/(su + 1e-16f);
    STb[(j0+0)*QS3 + r0+1] = a0*inv; STb[(j0+1)*QS3 + r0+1] = a1*inv; STb[(j0+2)*QS3 + r0+1] = a2*inv;
    a0 = s20*0.125f; a1 = s21*0.125f; a2 = s22*0.125f;
    m0 = fmaxf(fmaxf(a0, a1), a2);
    #pragma unroll
    for(int o = 1; o < 8; o <<= 1) m0 = fmaxf(m0, __shfl_xor(m0, o, 8));
    a0 = __expf(a0-m0); a1 = __expf(a1-m0); a2 = __expf(a2-m0);
    su = a0 + a1 + a2;
    #pragma unroll
    for(int o = 1; o < 8; o <<= 1) su += __shfl_xor(su, o, 8);
    inv = 1.0f/(su + 1e-16f);
    STb[(j0+0)*QS3 + r0+2] = a0*inv; STb[(j0+1)*QS3 + r0+2] = a1*inv; STb[(j0+2)*QS3 + r0+2] = a2*inv;
  }
  for(int i = t; i < GSIZE*DH; i += 512) hv[i] = 0.f;  // K region dead post-bar4
  __syncthreads();                                    // bar5: ST ready + hv zeroed

  // ---- PV: lane l = dim d; rows half*12..+11 (full j loop, R17 order)
  {
    float o12[12];
    #pragma unroll
    for(int r = 0; r < 12; ++r) o12[r] = 0.f;
    const float* vp  = qlds + 2*GSIZE*QS3 + hh*64 + l;
    const float* STb = qlds + hh*64;
    int rb = half*12;
    #pragma unroll
    for(int j = 0; j < GSIZE; ++j){
      float v = vp[j*QS3];
      #pragma unroll
      for(int rq = 0; rq < 3; ++rq){
        float4 p4 = *(const float4*)(STb + j*QS3 + rb + rq*4);
        o12[rq*4+0] = fmaf(p4.x, v, o12[rq*4+0]);
        o12[rq*4+1] = fmaf(p4.y, v, o12[rq*4+1]);
        o12[rq*4+2] = fmaf(p4.z, v, o12[rq*4+2]);
        o12[rq*4+3] = fmaf(p4.w, v, o12[rq*4+3]);
      }
    }
    #pragma unroll
    for(int r = 0; r < 12; ++r) atomicAdd(&hv[(rb + r)*DH + l], o12[r]);
  }
  __syncthreads();                                    // bar6: 4 heads accumulated

  // ---- tail: block's 4-head partial -> global hcomb atomics
  #pragma unroll
  for(int sl = 0; sl < 3; ++sl){
    int idx = t + sl*512;
    int r = idx >> 6, d = idx & 63;
    atomicAdd(&hcomb[(size_t)(base + r)*DH + d], hv[r*DH + d]*0.125f);
  }
}

// ================= K2.5: k_hfix =================
// hcomb += residual fold; HS column stats via atomics. 192 blocks x 32 rows.
__global__ __launch_bounds__(256)
void k_hfix(const float* __restrict__ x, float* __restrict__ ws,
            float* __restrict__ hcomb){
  __shared__ float redA[256], redB[256];
  int t = threadIdx.x, b = blockIdx.x;
  int d = t & 63, rg = t >> 6;
  int r0 = b*32 + rg*8;
  float s1 = 0.f, s2 = 0.f;
  #pragma unroll
  for(int k = 0; k < 8; ++k){
    int r = r0 + k;
    const float* xr = x + (size_t)r*DIN;
    float v = hcomb[(size_t)r*DH + d] + xr[d] + xr[64 + d];
    hcomb[(size_t)r*DH + d] = v;
    s1 += v; s2 += v*v;
  }
  redA[t] = s1; redB[t] = s2;
  __syncthreads();
  if(t < 64){
    float a1 = redA[t] + redA[t+64] + redA[t+128] + redA[t+192];
    float a2 = redB[t] + redB[t+64] + redB[t+128] + redB[t+192];
    atomicAdd(&ws[HS + t],      a1);
    atomicAdd(&ws[HS + 64 + t], a2);
  }
}

// ================= K3: k_final (R19 512-thr version) =================
__global__ __launch_bounds__(512)
void k_final(const float* __restrict__ x,
             const float* __restrict__ hbuf, const float* __restrict__ ws,
             const float* __restrict__ no_w, const float* __restrict__ no_b,
             const float* __restrict__ no_ms,
             const float* __restrict__ pn_w, const float* __restrict__ pn_b,
             const float* __restrict__ pn_ms,
             float* __restrict__ out){
  __shared__ __align__(16) float W1[4096];
  __shared__ __align__(16) float W2[4096];
  __shared__ __align__(16) float PW1[4096];
  __shared__ __align__(16) float fbs[260];
  __shared__ __align__(16) float hs[GSIZE][68];
  __shared__ __align__(16) float hn[GSIZE][68];
  __shared__ __align__(16) float ts[GSIZE][68];
  __shared__ float A2s[DH], C2s[DH];
  __shared__ float a3[DH], c3[DH];
  __shared__ float scores[GSIZE], wsm[GSIZE];

  int t = threadIdx.x;
  int base = blockIdx.x * GSIZE;
  int c = t & 63, i0 = t >> 6;      // rows i0+8r, r=0..2

  {
    const float4* s1 = (const float4*)(ws + WT1);
    const float4* s2 = (const float4*)(ws + WT2);
    const float4* s3 = (const float4*)(ws + PWT1);
    #pragma unroll
    for(int it = 0; it < 2; ++it){
      int i = t + it*512;
      ((float4*)W1)[i]  = s1[i];
      ((float4*)W2)[i]  = s2[i];
      ((float4*)PW1)[i] = s3[i];
    }
    if(t < 257) fbs[t] = ws[FBo + t];
    if(t < DH){
      float a1 = ws[HS + t];
      float a2 = ws[HS + 64 + t];
      float mean = a1 * (1.0f / N_NODES);
      float ex2  = a2 * (1.0f / N_NODES);
      float cm   = mean * no_ms[t];
      float var  = ex2 - 2.f*cm*mean + cm*cm;
      float rstd = rsqrtf(var + EPSN);
      float a    = no_w[t] * rstd;
      A2s[t] = a; C2s[t] = no_b[t] - a*cm;
    }
  }
  __syncthreads();
  {
    float a2 = A2s[c];
    float c2 = C2s[c];
    #pragma unroll
    for(int r = 0; r < 3; ++r){
      int i = i0 + 8*r;
      float hvv = hbuf[(size_t)(base + i)*DH + c];
      hs[i][c] = hvv;
      hn[i][c] = a2*hvv + c2;
    }
  }
  __syncthreads();

  {
    float acc[3];
    #pragma unroll
    for(int r = 0; r < 3; ++r) acc[r] = fbs[c];
    #pragma unroll 16
    for(int k = 0; k < DH; ++k){
      float w = W1[k*DH + c];
      #pragma unroll
      for(int r = 0; r < 3; ++r) acc[r] = fmaf(hn[i0 + 8*r][k], w, acc[r]);
    }
    #pragma unroll
    for(int r = 0; r < 3; ++r) ts[i0 + 8*r][c] = gelu_exact(acc[r]);
  }
  __syncthreads();

  {
    float acc[3];
    #pragma unroll
    for(int r = 0; r < 3; ++r) acc[r] = fbs[64 + c];
    #pragma unroll 16
    for(int k = 0; k < DH; ++k){
      float w = W2[k*DH + c];
      #pragma unroll
      for(int r = 0; r < 3; ++r) acc[r] = fmaf(ts[i0 + 8*r][k], w, acc[r]);
    }
    #pragma unroll
    for(int r = 0; r < 3; ++r) hs[i0 + 8*r][c] += acc[r];
  }
  __syncthreads();

  if(t < DH){
    float s1 = 0.f, s2 = 0.f;
    #pragma unroll
    for(int i = 0; i < GSIZE; i++){ float v = hs[i][t]; s1 += v; s2 += v*v; }
    float mean = s1 * (1.0f / GSIZE);
    float ex2  = s2 * (1.0f / GSIZE);
    float cm   = mean * pn_ms[t];
    float var  = ex2 - 2.f*cm*mean + cm*cm;
    float rstd = rsqrtf(var + EPSN);
    float a    = pn_w[t] * rstd;
    a3[t] = a; c3[t] = pn_b[t] - a*cm;
  }
  __syncthreads();

  {
    float acc[3];
    #pragma unroll
    for(int r = 0; r < 3; ++r) acc[r] = fbs[128 + c];
    #pragma unroll 16
    for(int k = 0; k < DH; ++k){
      float w  = PW1[k*DH + c];
      float ak = a3[k], ck = c3[k];
      #pragma unroll
      for(int r = 0; r < 3; ++r){
        float hnv = fmaf(ak, hs[i0 + 8*r][k], ck);
        acc[r] = fmaf(hnv, w, acc[r]);
      }
    }
    #pragma unroll
    for(int r = 0; r < 3; ++r) ts[i0 + 8*r][c] = gelu_exact(acc[r]);
  }
  __syncthreads();

  if(t < GSIZE){
    const float4* tp = (const float4*)ts[t];
    const float4* wp = (const float4*)(fbs + 192);
    float s = fbs[256];
    #pragma unroll
    for(int q = 0; q < 16; ++q){
      float4 a = tp[q], b = wp[q];
      s += a.x*b.x + a.y*b.y + a.z*b.z + a.w*b.w;
    }
    scores[t] = s;
  }
  __syncthreads();
  if(t < GSIZE){
    float mx = -1e30f;
    #pragma unroll
    for(int j = 0; j < GSIZE; j++) mx = fmaxf(mx, scores[j]);
    float sum = 0.f;
    #pragma unroll
    for(int j = 0; j < GSIZE; j++) sum += __expf(scores[j] - mx);
    wsm[t] = __expf(scores[t] - mx) / (sum + 1e-16f);
  }
  __syncthreads();
  if(t < DIN){
    float s = 0.f;
    #pragma unroll 8
    for(int i = 0; i < GSIZE; i++) s += wsm[i] * x[(size_t)(base+i)*DIN + t];
    out[(size_t)blockIdx.x*DIN + t] = s;
  }
}

extern "C" void kernel_launch(void* const* d_in, const int* in_sizes, int n_in,
                              void* d_out, int out_size, void* d_ws, size_t ws_size,
                              hipStream_t stream){
  (void)in_sizes; (void)n_in; (void)out_size; (void)ws_size;
  const float* x    = (const float*)d_in[0];
  const float* nq_w = (const float*)d_in[4];
  const float* nq_b = (const float*)d_in[5];
  const float* nq_ms= (const float*)d_in[6];
  const float* wq   = (const float*)d_in[7];
  const float* bq   = (const float*)d_in[8];
  const float* wk   = (const float*)d_in[9];
  const float* bk   = (const float*)d_in[10];
  const float* wv   = (const float*)d_in[11];
  const float* bv   = (const float*)d_in[12];
  const float* no_w = (const float*)d_in[13];
  const float* no_b = (const float*)d_in[14];
  const float* no_ms= (const float*)d_in[15];
  const float* o_w1 = (const float*)d_in[16];
  const float* o_b1 = (const float*)d_in[17];
  const float* o_w2 = (const float*)d_in[18];
  const float* o_b2 = (const float*)d_in[19];
  const float* pn_w = (const float*)d_in[20];
  const float* pn_b = (const float*)d_in[21];
  const float* pn_ms= (const float*)d_in[22];
  const float* p_w1 = (const float*)d_in[23];
  const float* p_b1 = (const float*)d_in[24];
  const float* p_w2 = (const float*)d_in[25];
  const float* p_b2 = (const float*)d_in[26];

  float* ws    = (float*)d_ws;
  float* hcomb = ws + HCF;

  // zero XS + HS + hcomb (atomic accumulators; ws is poisoned)
  hipMemsetAsync(d_ws, 0, (size_t)(384 + N_NODES*DH)*sizeof(float), stream);
  k_pre<<<207, 256, 0, stream>>>(x, o_w1, o_w2, p_w1, o_b1, o_b2, p_b1, p_w2, p_b2,
                                 wq, wk, wv, ws);
  k_attn3<<<512, 512, 0, stream>>>(x, bq, bk, bv, nq_w, nq_b, nq_ms, ws, hcomb);
  k_hfix<<<192, 256, 0, stream>>>(x, ws, hcomb);
  k_final<<<NGRAPH, 512, 0, stream>>>(x, hcomb, ws, no_w, no_b, no_ms,
                                      pn_w, pn_b, pn_ms, (float*)d_out);
}

// Round 9
// 166.263 us; speedup vs baseline: 1.0787x; 1.0787x over previous
//
#include <hip/hip_runtime.h>
#include <stdint.h>

// FP32 in/out. bf16 only for MFMA operands.
// R22: revert to R19 base (167.0 best; R20/R21 proved >64KB-LDS workgroups
// stay 1/CU on this part -- concurrency lever dead: R18 spill, R20 LDS
// rounding, R21 no-coresidency + alias-serialization +8us). New single
// variable: PV consumes P from REGISTERS via v_readlane (P[r][j] lives at
// lane (r/3)*8+(j/3), reg [r%3][j%3]) -- deletes 27 ST stores + 144
// broadcast ds_read_b128 per wave from the shared LDS pipe (~16k CU-cyc at
// 2 waves/SIMD). j-ascending accumulation order kept -> bit-identical.
// Ledger: R21 hv-alias regression; R20 LDS-rounding no-coresidency; R19
// k_final 512thr (167.0); R18 1024-thr VGPR-64 spill; R17 atomic stats;
// R16 fuse qkv+attn; R10 launch_bounds min-waves spill -- NO 2nd arg.

#define N_NODES 6144
#define GSIZE 24
#define NGRAPH 256
#define DIN 128
#define DH 64
#define EFF 512
#define EPSN 1e-5f

typedef __attribute__((ext_vector_type(8))) __bf16 bf16x8;
typedef __attribute__((ext_vector_type(4))) float f32x4;
union U16B { uint4 u; bf16x8 v; unsigned short s[8]; };

__device__ inline unsigned short f2bf(float f){
  unsigned u = __float_as_uint(f);
  u += 0x7fff + ((u>>16)&1);
  return (unsigned short)(u>>16);
}
__device__ inline float gelu_exact(float x){ return 0.5f*x*(1.0f+erff(x*0.70710678118654752f)); }

// ---- workspace float offsets (R19 layout) ----
#define XS    0         // 256 floats: x col sum (128) + sumsq (128), ATOMIC
#define HS    256       // 128 floats: h col sum (64) + sumsq (64), ATOMIC
#define WT1   81920
#define WT2   86016
#define PWT1  90112
#define FBo   94208     // 257 floats
#define WCVT_BYTE  385024   // 3 x 512 x 128 bf16 = 393216 B
#define HCOMB_BYTE 778240   // 6144 x 64 fp32

#define QSTRIDE 516     // fp32 row stride for LDS QKV (padded)

// ================= K1: k_pre =================
__global__ __launch_bounds__(256)
void k_pre(const float* __restrict__ x,
           const float* __restrict__ o_w1, const float* __restrict__ o_w2,
           const float* __restrict__ p_w1,
           const float* __restrict__ o_b1, const float* __restrict__ o_b2,
           const float* __restrict__ p_b1, const float* __restrict__ p_w2,
           const float* __restrict__ p_b2,
           const float* __restrict__ wq, const float* __restrict__ wk,
           const float* __restrict__ wv,
           float* __restrict__ wsf){
  int t = threadIdx.x;
  int bi = blockIdx.x;
  if(bi < 192){
    int c = t & 127, h = t >> 7;
    float s = 0.f, q = 0.f;
    #pragma unroll
    for(int r = 0; r < 16; ++r){
      float v = x[(size_t)(bi*32 + h + 2*r)*DIN + c];
      s += v; q += v*v;
    }
    __shared__ float sm[256], sm2[256];
    sm[t] = s; sm2[t] = q;
    __syncthreads();
    if(t < 128){
      atomicAdd(&wsf[XS + t],       sm[t] + sm[t+128]);
      atomicAdd(&wsf[XS + 128 + t], sm2[t] + sm2[t+128]);
    }
    return;
  }
  if(bi < 195){
    const float* src; float* dst;
    if(bi == 192){ src = o_w1; dst = wsf + WT1; }
    else if(bi == 193){ src = o_w2; dst = wsf + WT2; }
    else { src = p_w1; dst = wsf + PWT1; }
    for(int p = t; p < DH*DH; p += 256){
      int r = p >> 6, c = p & 63;
      dst[c*DH + r] = src[p];
    }
    if(bi == 192){
      float* fb = wsf + FBo;
      if(t < 64){
        fb[t]       = o_b1[t];
        fb[64 + t]  = o_b2[t];
        fb[128 + t] = p_b1[t];
        fb[192 + t] = p_w2[t];
      }
      if(t == 0) fb[256] = p_b2[0];
    }
    return;
  }
  int j = bi - 195;               // 0..11
  int mat = j >> 2, seg = j & 3;
  const float* src = (mat==0) ? wq : (mat==1) ? wk : wv;
  unsigned short* dst = (unsigned short*)((char*)wsf + WCVT_BYTE)
                        + (size_t)mat*EFF*DIN + seg*16384;
  const float* sp = src + seg*16384;
  for(int e = t*8; e < 16384; e += 2048){
    float4 a = *(const float4*)(sp + e);
    float4 b = *(const float4*)(sp + e + 4);
    U16B o;
    o.s[0]=f2bf(a.x); o.s[1]=f2bf(a.y); o.s[2]=f2bf(a.z); o.s[3]=f2bf(a.w);
    o.s[4]=f2bf(b.x); o.s[5]=f2bf(b.y); o.s[6]=f2bf(b.z); o.s[7]=f2bf(b.w);
    *(uint4*)(dst + e) = o.u;
  }
}

// ---- QKV weight tile load/compute macros (static buffers; depth-2 pipeline)
#define LOADW(nt, W, B) do{ \
  const int mat_ = (nt)>>2, sub_ = (nt)&3; \
  const unsigned short* wp_ = wcvt + (size_t)mat_*EFF*DIN \
      + (size_t)(h*64 + sub_*16 + m)*DIN + lq*8; \
  W[0] = *(const uint4*)(wp_);      W[1] = *(const uint4*)(wp_ + 32); \
  W[2] = *(const uint4*)(wp_ + 64); W[3] = *(const uint4*)(wp_ + 96); \
  const float* bias_ = (mat_==0) ? bq : (mat_==1) ? bk : bv; \
  B = *(const float4*)(bias_ + h*64 + sub_*16 + lq*4); \
}while(0)

#define COMPW(nt, W, B) do{ \
  const int mat_ = (nt)>>2, sub_ = (nt)&3; \
  f32x4 a0_ = {0.f,0.f,0.f,0.f}, a1_ = {0.f,0.f,0.f,0.f}; \
  U16B w8_; \
  w8_.u = W[0]; \
  a0_ = __builtin_amdgcn_mfma_f32_16x16x32_bf16(w8_.v, afr[0][0], a0_, 0, 0, 0); \
  a1_ = __builtin_amdgcn_mfma_f32_16x16x32_bf16(w8_.v, afr[1][0], a1_, 0, 0, 0); \
  w8_.u = W[1]; \
  a0_ = __builtin_amdgcn_mfma_f32_16x16x32_bf16(w8_.v, afr[0][1], a0_, 0, 0, 0); \
  a1_ = __builtin_amdgcn_mfma_f32_16x16x32_bf16(w8_.v, afr[1][1], a1_, 0, 0, 0); \
  w8_.u = W[2]; \
  a0_ = __builtin_amdgcn_mfma_f32_16x16x32_bf16(w8_.v, afr[0][2], a0_, 0, 0, 0); \
  a1_ = __builtin_amdgcn_mfma_f32_16x16x32_bf16(w8_.v, afr[1][2], a1_, 0, 0, 0); \
  w8_.u = W[3]; \
  a0_ = __builtin_amdgcn_mfma_f32_16x16x32_bf16(w8_.v, afr[0][3], a0_, 0, 0, 0); \
  a1_ = __builtin_amdgcn_mfma_f32_16x16x32_bf16(w8_.v, afr[1][3], a1_, 0, 0, 0); \
  float* dst_ = qlds + mat_*(GSIZE*QSTRIDE); \
  const int col_ = h*64 + sub_*16 + lq*4; \
  { float4 o_; o_.x=a0_[0]+B.x; o_.y=a0_[1]+B.y; o_.z=a0_[2]+B.z; o_.w=a0_[3]+B.w; \
    *(float4*)(dst_ + m*QSTRIDE + col_) = o_; } \
  if(m < 8){ float4 o_; o_.x=a1_[0]+B.x; o_.y=a1_[1]+B.y; o_.z=a1_[2]+B.z; o_.w=a1_[3]+B.w; \
    *(float4*)(dst_ + (16+m)*QSTRIDE + col_) = o_; } \
}while(0)

// ================= K2: k_attn2 =================
// R19 structure; PV now reads P from registers via v_readlane (no ST stores,
// no P LDS re-reads). P[r][j] lives at lane (r/3)*8+(j/3), reg pr[r%3][j%3].
__global__ __launch_bounds__(512)
void k_attn2(const float* __restrict__ x,
             const float* __restrict__ bq, const float* __restrict__ bk,
             const float* __restrict__ bv,
             const float* __restrict__ nq_w, const float* __restrict__ nq_b,
             const float* __restrict__ nq_ms,
             float* __restrict__ ws, float* __restrict__ hcomb){
  __shared__ __align__(16) float qlds[3*GSIZE*QSTRIDE];  // 148,608 B
  __shared__ __align__(16) float hv[GSIZE][68];          // 6,528 B
  __shared__ float A1s[DIN], C1s[DIN];                   // 1,024 B

  int t = threadIdx.x, g = blockIdx.x, base = g*GSIZE;
  int h = t >> 6, l = t & 63;
  const unsigned short* wcvt = (const unsigned short*)((const char*)ws + WCVT_BYTE);

  for(int i = t; i < GSIZE*68; i += 512) ((float*)hv)[i] = 0.f;

  // ---- x-norm coeffs from atomic sums (2 loads/thread)
  if(t < 128){
    float s1 = ws[XS + t];
    float q1 = ws[XS + 128 + t];
    float mean = s1 * (1.0f / N_NODES);
    float ex2  = q1 * (1.0f / N_NODES);
    float cm   = mean * nq_ms[t];
    float var  = ex2 - 2.f*cm*mean + cm*cm;
    float rstd = rsqrtf(var + EPSN);
    float a    = nq_w[t] * rstd;
    A1s[t] = a; C1s[t] = nq_b[t] - a*cm;
  }
  __syncthreads();

  int m = l & 15, lq = l >> 4;

  // ---- A-fragments (xhat bf16), rows mt*16+m (clamped; garbage rows discarded)
  bf16x8 afr[2][4];
  #pragma unroll
  for(int mt = 0; mt < 2; ++mt){
    int row = mt*16 + m; if(row > GSIZE-1) row = GSIZE-1;
    const float* xr = x + (size_t)(base + row)*DIN;
    #pragma unroll
    for(int kk = 0; kk < 4; ++kk){
      int k0 = kk*32 + lq*8;
      float4 a = *(const float4*)(xr + k0);
      float4 b = *(const float4*)(xr + k0 + 4);
      U16B u;
      u.s[0] = f2bf(a.x*A1s[k0+0] + C1s[k0+0]);
      u.s[1] = f2bf(a.y*A1s[k0+1] + C1s[k0+1]);
      u.s[2] = f2bf(a.z*A1s[k0+2] + C1s[k0+2]);
      u.s[3] = f2bf(a.w*A1s[k0+3] + C1s[k0+3]);
      u.s[4] = f2bf(b.x*A1s[k0+4] + C1s[k0+4]);
      u.s[5] = f2bf(b.y*A1s[k0+5] + C1s[k0+5]);
      u.s[6] = f2bf(b.z*A1s[k0+6] + C1s[k0+6]);
      u.s[7] = f2bf(b.w*A1s[k0+7] + C1s[k0+7]);
      afr[mt][kk] = u.v;
    }
  }

  // ---- QKV GEMM per wave: head h's 192 out-cols, depth-2 prefetch pipeline
  {
    uint4 wA[4], wB[4], wC[4];
    float4 bA, bB, bC;
    LOADW(0, wA, bA);  LOADW(1, wB, bB);
    LOADW(2, wC, bC);  COMPW(0, wA, bA);
    LOADW(3, wA, bA);  COMPW(1, wB, bB);
    LOADW(4, wB, bB);  COMPW(2, wC, bC);
    LOADW(5, wC, bC);  COMPW(3, wA, bA);
    LOADW(6, wA, bA);  COMPW(4, wB, bB);
    LOADW(7, wB, bB);  COMPW(5, wC, bC);
    LOADW(8, wC, bC);  COMPW(6, wA, bA);
    LOADW(9, wA, bA);  COMPW(7, wB, bB);
    LOADW(10, wB, bB); COMPW(8, wC, bC);
    LOADW(11, wC, bC); COMPW(9, wA, bA);
    COMPW(10, wB, bB);
    COMPW(11, wC, bC);
  }
  // NO barrier: wave h reads only its own columns from here on.

  // ---- S + softmax (3x3 register-blocked, wave-local); P stays in registers
  float pr[3][3];
  {
    int r0 = 3*(l >> 3), j0 = 3*(l & 7);
    const float* qp = qlds + r0*QSTRIDE + h*64;
    const float* kp = qlds + GSIZE*QSTRIDE + j0*QSTRIDE + h*64;
    float s00=0.f,s01=0.f,s02=0.f,s10=0.f,s11=0.f,s12=0.f,s20=0.f,s21=0.f,s22=0.f;
    #pragma unroll
    for(int d4 = 0; d4 < 16; ++d4){
      float4 q0 = *(const float4*)(qp + d4*4);
      float4 q1 = *(const float4*)(qp + QSTRIDE + d4*4);
      float4 q2 = *(const float4*)(qp + 2*QSTRIDE + d4*4);
      float4 k0 = *(const float4*)(kp + d4*4);
      float4 k1 = *(const float4*)(kp + QSTRIDE + d4*4);
      float4 k2 = *(const float4*)(kp + 2*QSTRIDE + d4*4);
      s00 += q0.x*k0.x + q0.y*k0.y + q0.z*k0.z + q0.w*k0.w;
      s01 += q0.x*k1.x + q0.y*k1.y + q0.z*k1.z + q0.w*k1.w;
      s02 += q0.x*k2.x + q0.y*k2.y + q0.z*k2.z + q0.w*k2.w;
      s10 += q1.x*k0.x + q1.y*k0.y + q1.z*k0.z + q1.w*k0.w;
      s11 += q1.x*k1.x + q1.y*k1.y + q1.z*k1.z + q1.w*k1.w;
      s12 += q1.x*k2.x + q1.y*k2.y + q1.z*k2.z + q1.w*k2.w;
      s20 += q2.x*k0.x + q2.y*k0.y + q2.z*k0.z + q2.w*k0.w;
      s21 += q2.x*k1.x + q2.y*k1.y + q2.z*k1.z + q2.w*k1.w;
      s22 += q2.x*k2.x + q2.y*k2.y + q2.z*k2.z + q2.w*k2.w;
    }
    float a0, a1, a2, m0, su, inv;
    a0 = s00*0.125f; a1 = s01*0.125f; a2 = s02*0.125f;
    m0 = fmaxf(fmaxf(a0, a1), a2);
    #pragma unroll
    for(int o = 1; o < 8; o <<= 1) m0 = fmaxf(m0, __shfl_xor(m0, o, 8));
    a0 = __expf(a0-m0); a1 = __expf(a1-m0); a2 = __expf(a2-m0);
    su = a0 + a1 + a2;
    #pragma unroll
    for(int o = 1; o < 8; o <<= 1) su += __shfl_xor(su, o, 8);
    inv = 1.0f/(su + 1e-16f);
    pr[0][0] = a0*inv; pr[0][1] = a1*inv; pr[0][2] = a2*inv;
    a0 = s10*0.125f; a1 = s11*0.125f; a2 = s12*0.125f;
    m0 = fmaxf(fmaxf(a0, a1), a2);
    #pragma unroll
    for(int o = 1; o < 8; o <<= 1) m0 = fmaxf(m0, __shfl_xor(m0, o, 8));
    a0 = __expf(a0-m0); a1 = __expf(a1-m0); a2 = __expf(a2-m0);
    su = a0 + a1 + a2;
    #pragma unroll
    for(int o = 1; o < 8; o <<= 1) su += __shfl_xor(su, o, 8);
    inv = 1.0f/(su + 1e-16f);
    pr[1][0] = a0*inv; pr[1][1] = a1*inv; pr[1][2] = a2*inv;
    a0 = s20*0.125f; a1 = s21*0.125f; a2 = s22*0.125f;
    m0 = fmaxf(fmaxf(a0, a1), a2);
    #pragma unroll
    for(int o = 1; o < 8; o <<= 1) m0 = fmaxf(m0, __shfl_xor(m0, o, 8));
    a0 = __expf(a0-m0); a1 = __expf(a1-m0); a2 = __expf(a2-m0);
    su = a0 + a1 + a2;
    #pragma unroll
    for(int o = 1; o < 8; o <<= 1) su += __shfl_xor(su, o, 8);
    inv = 1.0f/(su + 1e-16f);
    pr[2][0] = a0*inv; pr[2][1] = a1*inv; pr[2][2] = a2*inv;
  }

  // ---- PV: lane l = output dim d; P via v_readlane broadcasts (pure VALU)
  // o24[r] += P[r][j]*V[j][l], j ascending (R17 summation order, bit-identical)
  {
    float o24[GSIZE];
    #pragma unroll
    for(int r = 0; r < GSIZE; ++r) o24[r] = 0.f;
    const float* vp = qlds + 2*GSIZE*QSTRIDE + h*64 + l;
    #pragma unroll
    for(int j = 0; j < GSIZE; ++j){
      float v = vp[j*QSTRIDE];
      const int jg = j/3, jj = j%3;           // constants after unroll
      #pragma unroll
      for(int rg = 0; rg < 8; ++rg){
        #pragma unroll
        for(int rr = 0; rr < 3; ++rr){
          float pv = __uint_as_float(
              __builtin_amdgcn_readlane(__float_as_uint(pr[rr][jj]), rg*8 + jg));
          o24[rg*3+rr] = fmaf(pv, v, o24[rg*3+rr]);
        }
      }
    }
    #pragma unroll
    for(int r = 0; r < GSIZE; ++r) atomicAdd(&hv[r][l], o24[r]);
  }
  __syncthreads();   // all heads accumulated

  // ---- combine: head mean + residual fold, write hcomb, rebuild hv
  #pragma unroll
  for(int sl = 0; sl < 3; ++sl){
    int idx = t + sl*512;
    int r = idx >> 6, d = idx & 63;
    const float* xr = x + (size_t)(base + r)*DIN;
    float hval = hv[r][d]*0.125f + xr[d] + xr[64 + d];
    hcomb[(size_t)(base + r)*DH + d] = hval;
    hv[r][d] = hval;
  }
  __syncthreads();
  if(t < 64){
    float s1 = 0.f, s2 = 0.f;
    #pragma unroll
    for(int i = 0; i < GSIZE; ++i){ float v = hv[i][t]; s1 += v; s2 += v*v; }
    atomicAdd(&ws[HS + t],      s1);
    atomicAdd(&ws[HS + 64 + t], s2);
  }
}

// ================= K3: k_final (R19 512-thr version) =================
__global__ __launch_bounds__(512)
void k_final(const float* __restrict__ x,
             const float* __restrict__ hbuf, const float* __restrict__ ws,
             const float* __restrict__ no_w, const float* __restrict__ no_b,
             const float* __restrict__ no_ms,
             const float* __restrict__ pn_w, const float* __restrict__ pn_b,
             const float* __restrict__ pn_ms,
             float* __restrict__ out){
  __shared__ __align__(16) float W1[4096];
  __shared__ __align__(16) float W2[4096];
  __shared__ __align__(16) float PW1[4096];
  __shared__ __align__(16) float fbs[260];
  __shared__ __align__(16) float hs[GSIZE][68];
  __shared__ __align__(16) float hn[GSIZE][68];
  __shared__ __align__(16) float ts[GSIZE][68];
  __shared__ float A2s[DH], C2s[DH];
  __shared__ float a3[DH], c3[DH];
  __shared__ float scores[GSIZE], wsm[GSIZE];

  int t = threadIdx.x;
  int base = blockIdx.x * GSIZE;
  int c = t & 63, i0 = t >> 6;      // rows i0+8r, r=0..2

  {
    const float4* s1 = (const float4*)(ws + WT1);
    const float4* s2 = (const float4*)(ws + WT2);
    const float4* s3 = (const float4*)(ws + PWT1);
    #pragma unroll
    for(int it = 0; it < 2; ++it){
      int i = t + it*512;
      ((float4*)W1)[i]  = s1[i];
      ((float4*)W2)[i]  = s2[i];
      ((float4*)PW1)[i] = s3[i];
    }
    if(t < 257) fbs[t] = ws[FBo + t];
    if(t < DH){
      float a1 = ws[HS + t];
      float a2 = ws[HS + 64 + t];
      float mean = a1 * (1.0f / N_NODES);
      float ex2  = a2 * (1.0f / N_NODES);
      float cm   = mean * no_ms[t];
      float var  = ex2 - 2.f*cm*mean + cm*cm;
      float rstd = rsqrtf(var + EPSN);
      float a    = no_w[t] * rstd;
      A2s[t] = a; C2s[t] = no_b[t] - a*cm;
    }
  }
  __syncthreads();
  {
    float a2 = A2s[c];
    float c2 = C2s[c];
    #pragma unroll
    for(int r = 0; r < 3; ++r){
      int i = i0 + 8*r;
      float hvv = hbuf[(size_t)(base + i)*DH + c];
      hs[i][c] = hvv;
      hn[i][c] = a2*hvv + c2;
    }
  }
  __syncthreads();

  {
    float acc[3];
    #pragma unroll
    for(int r = 0; r < 3; ++r) acc[r] = fbs[c];
    #pragma unroll 16
    for(int k = 0; k < DH; ++k){
      float w = W1[k*DH + c];
      #pragma unroll
      for(int r = 0; r < 3; ++r) acc[r] = fmaf(hn[i0 + 8*r][k], w, acc[r]);
    }
    #pragma unroll
    for(int r = 0; r < 3; ++r) ts[i0 + 8*r][c] = gelu_exact(acc[r]);
  }
  __syncthreads();

  {
    float acc[3];
    #pragma unroll
    for(int r = 0; r < 3; ++r) acc[r] = fbs[64 + c];
    #pragma unroll 16
    for(int k = 0; k < DH; ++k){
      float w = W2[k*DH + c];
      #pragma unroll
      for(int r = 0; r < 3; ++r) acc[r] = fmaf(ts[i0 + 8*r][k], w, acc[r]);
    }
    #pragma unroll
    for(int r = 0; r < 3; ++r) hs[i0 + 8*r][c] += acc[r];
  }
  __syncthreads();

  if(t < DH){
    float s1 = 0.f, s2 = 0.f;
    #pragma unroll
    for(int i = 0; i < GSIZE; i++){ float v = hs[i][t]; s1 += v; s2 += v*v; }
    float mean = s1 * (1.0f / GSIZE);
    float ex2  = s2 * (1.0f / GSIZE);
    float cm   = mean * pn_ms[t];
    float var  = ex2 - 2.f*cm*mean + cm*cm;
    float rstd = rsqrtf(var + EPSN);
    float a    = pn_w[t] * rstd;
    a3[t] = a; c3[t] = pn_b[t] - a*cm;
  }
  __syncthreads();

  {
    float acc[3];
    #pragma unroll
    for(int r = 0; r < 3; ++r) acc[r] = fbs[128 + c];
    #pragma unroll 16
    for(int k = 0; k < DH; ++k){
      float w  = PW1[k*DH + c];
      float ak = a3[k], ck = c3[k];
      #pragma unroll
      for(int r = 0; r < 3; ++r){
        float hnv = fmaf(ak, hs[i0 + 8*r][k], ck);
        acc[r] = fmaf(hnv, w, acc[r]);
      }
    }
    #pragma unroll
    for(int r = 0; r < 3; ++r) ts[i0 + 8*r][c] = gelu_exact(acc[r]);
  }
  __syncthreads();

  if(t < GSIZE){
    const float4* tp = (const float4*)ts[t];
    const float4* wp = (const float4*)(fbs + 192);
    float s = fbs[256];
    #pragma unroll
    for(int q = 0; q < 16; ++q){
      float4 a = tp[q], b = wp[q];
      s += a.x*b.x + a.y*b.y + a.z*b.z + a.w*b.w;
    }
    scores[t] = s;
  }
  __syncthreads();
  if(t < GSIZE){
    float mx = -1e30f;
    #pragma unroll
    for(int j = 0; j < GSIZE; j++) mx = fmaxf(mx, scores[j]);
    float sum = 0.f;
    #pragma unroll
    for(int j = 0; j < GSIZE; j++) sum += __expf(scores[j] - mx);
    wsm[t] = __expf(scores[t] - mx) / (sum + 1e-16f);
  }
  __syncthreads();
  if(t < DIN){
    float s = 0.f;
    #pragma unroll 8
    for(int i = 0; i < GSIZE; i++) s += wsm[i] * x[(size_t)(base+i)*DIN + t];
    out[(size_t)blockIdx.x*DIN + t] = s;
  }
}

extern "C" void kernel_launch(void* const* d_in, const int* in_sizes, int n_in,
                              void* d_out, int out_size, void* d_ws, size_t ws_size,
                              hipStream_t stream){
  (void)in_sizes; (void)n_in; (void)out_size; (void)ws_size;
  const float* x    = (const float*)d_in[0];
  const float* nq_w = (const float*)d_in[4];
  const float* nq_b = (const float*)d_in[5];
  const float* nq_ms= (const float*)d_in[6];
  const float* wq   = (const float*)d_in[7];
  const float* bq   = (const float*)d_in[8];
  const float* wk   = (const float*)d_in[9];
  const float* bk   = (const float*)d_in[10];
  const float* wv   = (const float*)d_in[11];
  const float* bv   = (const float*)d_in[12];
  const float* no_w = (const float*)d_in[13];
  const float* no_b = (const float*)d_in[14];
  const float* no_ms= (const float*)d_in[15];
  const float* o_w1 = (const float*)d_in[16];
  const float* o_b1 = (const float*)d_in[17];
  const float* o_w2 = (const float*)d_in[18];
  const float* o_b2 = (const float*)d_in[19];
  const float* pn_w = (const float*)d_in[20];
  const float* pn_b = (const float*)d_in[21];
  const float* pn_ms= (const float*)d_in[22];
  const float* p_w1 = (const float*)d_in[23];
  const float* p_b1 = (const float*)d_in[24];
  const float* p_w2 = (const float*)d_in[25];
  const float* p_b2 = (const float*)d_in[26];

  float* ws    = (float*)d_ws;
  float* hcomb = (float*)((char*)d_ws + HCOMB_BYTE);

  // zero the atomic accumulators (XS 256 + HS 128 floats; ws is poisoned)
  hipMemsetAsync(d_ws, 0, 384*sizeof(float), stream);
  k_pre<<<207, 256, 0, stream>>>(x, o_w1, o_w2, p_w1, o_b1, o_b2, p_b1, p_w2, p_b2,
                                 wq, wk, wv, ws);
  k_attn2<<<NGRAPH, 512, 0, stream>>>(x, bq, bk, bv, nq_w, nq_b, nq_ms, ws, hcomb);
  k_final<<<NGRAPH, 512, 0, stream>>>(x, hcomb, ws, no_w, no_b, no_ms,
                                      pn_w, pn_b, pn_ms, (float*)d_out);
}